// Round 20
// baseline (250.464 us; speedup 1.0000x reference)
//
#include <hip/hip_runtime.h>
#include <math.h>

#define B_  32
#define L_  1024
#define D_  512
#define H_  8
#define G_  65
#define K_  16
#define DH_ 64
#define HG_  (H_ * G_)   // 520
#define HGP2_ 640        // padded p rows (40 m-tiles of 16)
#define BL_  (B_ * L_)   // 32768
#define NROW_ (B_ * H_ * G_)  // 16640
#define M_OUT_ (B_ * G_)      // 2080

typedef _Float16 f16x8 __attribute__((ext_vector_type(8)));
typedef float f32x4 __attribute__((ext_vector_type(4)));

__device__ __forceinline__ unsigned int f2s(float f) {
  unsigned int u = __float_as_uint(f);
  return (u & 0x80000000u) ? ~u : (u | 0x80000000u);
}
__device__ __forceinline__ float s2f(unsigned int u) {
  return __uint_as_float((u & 0x80000000u) ? (u & 0x7FFFFFFFu) : ~u);
}
// fp16 2-plane split, flush-safe: both planes are normal-or-zero fp16 (lo is
// pre-scaled by 2^12). value ~= hi + lo*2^-12 with rel err ~2^-24.
__device__ __forceinline__ void split16(float v, _Float16* h, _Float16* l) {
  _Float16 h0 = (_Float16)v;
  float hf = (float)h0;
  if (fabsf(v) < 6.103515625e-05f) { h0 = (_Float16)0.f; hf = 0.f; }
  *h = h0;
  *l = (_Float16)((v - hf) * 4096.0f);
}
__device__ __forceinline__ void gload16(const void* g, void* l) {
  __builtin_amdgcn_global_load_lds(
      (const __attribute__((address_space(1))) unsigned int*)g,
      (__attribute__((address_space(3))) unsigned int*)l, 16, 0, 0);
}
// packed-fragment index: fragment (tile mt, k-chunk kc), lane slot, 8 elems.
// element (row, c): mt=row>>4, kc=c>>5, lane=((c&31)>>3)*16 + (row&15), e=c&7.
__device__ __forceinline__ size_t pk_idx(int row, int c) {
  return (((size_t)(row >> 4) * 16 + (c >> 5)) << 9) +
         ((((c & 31) >> 3) << 4) + (row & 15)) * 8 + (c & 7);
}

// 1) t = log(relu(x)+1) -> fp16 hi + fp16 scaled-lo
__global__ void transform_split_kernel(const float* __restrict__ x,
                                       _Float16* __restrict__ th16,
                                       _Float16* __restrict__ tl16, int n4) {
  int i = blockIdx.x * blockDim.x + threadIdx.x;
  int stride = gridDim.x * blockDim.x;
  const float4* x4 = (const float4*)x;
  for (; i < n4; i += stride) {
    float4 a = x4[i];
    float t[4];
    t[0] = logf(fmaxf(a.x, 0.f) + 1.f);
    t[1] = logf(fmaxf(a.y, 0.f) + 1.f);
    t[2] = logf(fmaxf(a.z, 0.f) + 1.f);
    t[3] = logf(fmaxf(a.w, 0.f) + 1.f);
    _Float16 h[4], l[4];
#pragma unroll
    for (int j = 0; j < 4; ++j) split16(t[j], &h[j], &l[j]);
    *(ushort4*)&th16[i * 4] = *(ushort4*)h;
    *(ushort4*)&tl16[i * 4] = *(ushort4*)l;
  }
}

// 2) Wv,Wo -> PACKED-fragment fp16 B-operands (contiguous 1KB per fragment)
__global__ __launch_bounds__(256) void wprep_kernel(const float* __restrict__ Wv,
                                                    const float* __restrict__ Wo,
                                                    _Float16* __restrict__ wvtp,
                                                    _Float16* __restrict__ wotp) {
  int n = blockIdx.x;
  for (int k = threadIdx.x; k < 512; k += 256) {
    size_t o = pk_idx(n, k);
    wvtp[o] = (_Float16)Wv[(size_t)k * 512 + n];
    wotp[o] = (_Float16)Wo[(size_t)k * 512 + n];
  }
}

// 3) q = target @ Wq + bq   [G,512] fp32
__global__ __launch_bounds__(256) void qproj_kernel(const float* __restrict__ target,
                                                    const float* __restrict__ Wq,
                                                    const float* __restrict__ bq,
                                                    float* __restrict__ q) {
  int g = blockIdx.x;
  int d = blockIdx.y * 256 + threadIdx.x;
  __shared__ float ts[512];
  for (int i = threadIdx.x; i < 512; i += 256) ts[i] = target[g * 512 + i];
  __syncthreads();
  float acc = bq[d];
  for (int c = 0; c < 512; ++c) acc += ts[c] * Wq[c * 512 + d];
  q[g * 512 + d] = acc;
}

// 4) p[hg][c] -> PACKED fp16 hi/lo planes. One thread per 2 outputs,
//    16 independent float4 loads (r19-proven). rows 520..639 zeroed.
__global__ __launch_bounds__(256) void p_kernel(const float* __restrict__ q,
                                                const float* __restrict__ Wk,
                                                _Float16* __restrict__ pph,
                                                _Float16* __restrict__ ppl) {
  int hg = blockIdx.x;
  int tid = threadIdx.x;
  if (hg >= HG_) {
    for (int c = tid; c < 512; c += 256) {
      size_t o = pk_idx(hg, c);
      pph[o] = (_Float16)0.f;
      ppl[o] = (_Float16)0.f;
    }
    return;
  }
  int h = hg / G_, g = hg % G_;
  __shared__ float4 qs[16];
  if (tid < 16) qs[tid] = *(const float4*)&q[g * 512 + h * 64 + tid * 4];
  __syncthreads();
#pragma unroll
  for (int cc = 0; cc < 2; ++cc) {
    int c = cc * 256 + tid;
    const float4* wr = (const float4*)&Wk[(size_t)c * 512 + h * 64];
    float acc = 0.f;
#pragma unroll
    for (int jj = 0; jj < 16; ++jj) {
      float4 wv = wr[jj];
      float4 qv = qs[jj];
      acc += wv.x * qv.x + wv.y * qv.y + wv.z * qv.z + wv.w * qv.w;
    }
    _Float16 hh, ll;
    split16(acc, &hh, &ll);
    size_t o = pk_idx(hg, c);
    pph[o] = hh;
    ppl[o] = ll;
  }
}

// 5) scores GEMM: S = p . t, fp16 2-plane / 3-product. 3-BUFFER rotation +
//    counted s_waitcnt vmcnt(7) + raw s_barrier (T3/T4): stage k+2 while
//    computing k; loads stay in flight across barriers (no vmcnt(0) drains —
//    the last structural residual). LDS 3 x 28KB = 84KB, 1 block/CU.
__global__ __launch_bounds__(256) void scores_gemm_kernel(
    const _Float16* __restrict__ th16, const _Float16* __restrict__ tl16,
    const _Float16* __restrict__ pph, const _Float16* __restrict__ ppl,
    float* __restrict__ scores) {
  __shared__ char lds[86016];  // 3 bufs x {t: 2x8KB, A: 12KB}
  const int w = blockIdx.x;
  const int xcd = w & 7;
  const int j = w >> 3;
  const int n0 = (xcd * 32 + j / 6) * 128;
  const int m0 = (j % 6) * 96;
  const int mt0 = (j % 6) * 6;          // m0/16
  const int tid = threadIdx.x;
  const int lane = tid & 63;
  const int wid = tid >> 6;
  const int l16 = lane & 15;
  const int lg = lane >> 4;

  f32x4 acc0[6][2], acc1[6][2];
#pragma unroll
  for (int i = 0; i < 6; ++i)
#pragma unroll
    for (int jj = 0; jj < 2; ++jj) { acc0[i][jj] = (f32x4)(0.f); acc1[i][jj] = (f32x4)(0.f); }

  const int st_row = wid * 16 + (lane >> 2);
  const int st_s   = lane & 3;

  // 7 gload16 per thread per stage: t (4) then A (3)
#define STAGE_SC(buf, ks)                                                      \
  {                                                                            \
    _Pragma("unroll")                                                          \
    for (int it = 0; it < 2; ++it) {                                           \
      int row = it * 64 + st_row;                                              \
      size_t src = (size_t)(n0 + row) * 512 + (ks) * 32 +                      \
                   ((st_s ^ (row & 3)) << 3);                                  \
      char* dst = lds + (buf) * 28672 + it * 4096 + wid * 1024;                \
      gload16(th16 + src, dst);                                                \
      gload16(tl16 + src, dst + 8192);                                         \
    }                                                                          \
    _Pragma("unroll")                                                          \
    for (int i = 0; i < 3; ++i) {                                              \
      int f = wid * 3 + i;            /* 0..11: 0-5 hi, 6-11 lo */             \
      int fm = f >= 6 ? f - 6 : f;                                             \
      const _Float16* sp = (f >= 6) ? ppl : pph;                               \
      size_t src = (((size_t)(mt0 + fm) * 16 + (ks)) << 9) + lane * 8;         \
      gload16(sp + src, lds + (buf) * 28672 + 16384 + f * 1024);               \
    }                                                                          \
  }

  STAGE_SC(0, 0);
  STAGE_SC(1, 1);
  __syncthreads();           // full drain: buf0, buf1 ready

#pragma unroll
  for (int ks = 0; ks < 16; ++ks) {
    const int cur = ks % 3;
    if (ks + 2 < 16) STAGE_SC((ks + 2) % 3, ks + 2);
    // A fragments from LDS (linear, lane*16 -> conflict-free)
    const char* abase = lds + cur * 28672 + 16384;
    f16x8 Ah[6], Al[6];
#pragma unroll
    for (int fm = 0; fm < 6; ++fm) {
      Ah[fm] = *(const f16x8*)(abase + fm * 1024 + lane * 16);
      Al[fm] = *(const f16x8*)(abase + (6 + fm) * 1024 + lane * 16);
    }
    // B fragments from current t buffer
    f16x8 Bh[2], Bl[2];
#pragma unroll
    for (int fn = 0; fn < 2; ++fn) {
      int r = wid * 32 + fn * 16 + l16;
      int addr = cur * 28672 + r * 64 + ((lg ^ (r & 3)) << 4);
      Bh[fn] = *(const f16x8*)(lds + addr);
      Bl[fn] = *(const f16x8*)(lds + addr + 8192);
    }
#pragma unroll
    for (int fm = 0; fm < 6; ++fm) {
#pragma unroll
      for (int fn = 0; fn < 2; ++fn) {
        acc0[fm][fn] = __builtin_amdgcn_mfma_f32_16x16x32_f16(Ah[fm], Bh[fn], acc0[fm][fn], 0, 0, 0);
        acc1[fm][fn] = __builtin_amdgcn_mfma_f32_16x16x32_f16(Ah[fm], Bl[fn], acc1[fm][fn], 0, 0, 0);
        acc1[fm][fn] = __builtin_amdgcn_mfma_f32_16x16x32_f16(Al[fm], Bh[fn], acc1[fm][fn], 0, 0, 0);
      }
    }
    // counted wait: next buffer's loads (issued at ks-1) must retire; the 7
    // issued THIS step may stay in flight. Tail: ks=14 issued nothing new ->
    // full drain; ks=15 is last (no wait needed).
    if (ks < 14) {
      asm volatile("s_waitcnt vmcnt(7)" ::: "memory");
      __builtin_amdgcn_s_barrier();
      __builtin_amdgcn_sched_barrier(0);
    } else if (ks == 14) {
      asm volatile("s_waitcnt vmcnt(0)" ::: "memory");
      __builtin_amdgcn_s_barrier();
      __builtin_amdgcn_sched_barrier(0);
    }
  }
#undef STAGE_SC

#pragma unroll
  for (int fm = 0; fm < 6; ++fm) {
    int hg0 = m0 + fm * 16 + ((lane >> 4) << 2);
#pragma unroll
    for (int fn = 0; fn < 2; ++fn) {
      int col = n0 + wid * 32 + fn * 16 + l16;
#pragma unroll
      for (int r = 0; r < 4; ++r) {
        int row = hg0 + r;
        if (row < HG_)
          scores[(size_t)row * BL_ + col] =
              acc0[fm][fn][r] + acc1[fm][fn][r] * 0.000244140625f;
      }
    }
  }
}

// 6) V GEMM: fp16 1-term, PACKED B-loads (contiguous 1KB fragments).
__global__ __launch_bounds__(256, 2) void vgemm_kernel(
    const _Float16* __restrict__ th16, const _Float16* __restrict__ wvtp,
    const float* __restrict__ bv, _Float16* __restrict__ vout) {
  __shared__ char lds[16384];  // t_hi tile [128][64] fp16, slot-swizzled
  const int tid = threadIdx.x;
  const int lane = tid & 63;
  const int wid = tid >> 6;
  const int wave_m = wid >> 1;
  const int wave_n = wid & 1;
  const int m0 = blockIdx.x * 128;
  const int n0 = blockIdx.y * 128;

  f32x4 acc[4][4];
#pragma unroll
  for (int i = 0; i < 4; ++i)
#pragma unroll
    for (int j = 0; j < 4; ++j) acc[i][j] = (f32x4)(0.f);

  for (int k0 = 0; k0 < 512; k0 += 64) {
#pragma unroll
    for (int it = 0; it < 4; ++it) {
      int row = it * 32 + (tid >> 3);
      int j = tid & 7;
      size_t src = (size_t)(m0 + row) * 512 + k0 + ((j ^ (row & 7)) << 3);
      gload16(th16 + src, lds + it * 4096 + wid * 1024);
    }
    __syncthreads();
#pragma unroll
    for (int kh = 0; kh < 2; ++kh) {
      f16x8 Bv[4];
#pragma unroll
      for (int fn = 0; fn < 4; ++fn) {
        size_t bo = (((size_t)(n0 >> 4) + wave_n * 4 + fn) * 16 +
                     (k0 >> 5) + kh) * 512 + lane * 8;
        Bv[fn] = *(const f16x8*)(wvtp + bo);
      }
#pragma unroll
      for (int fm = 0; fm < 4; ++fm) {
        int r = wave_m * 64 + fm * 16 + (lane & 15);
        int jl = kh * 4 + (lane >> 4);
        f16x8 Af = *(const f16x8*)(lds + r * 128 + ((jl ^ (r & 7)) << 4));
#pragma unroll
        for (int fn = 0; fn < 4; ++fn)
          acc[fm][fn] = __builtin_amdgcn_mfma_f32_16x16x32_f16(Af, Bv[fn], acc[fm][fn], 0, 0, 0);
      }
    }
    __syncthreads();
  }
#pragma unroll
  for (int fm = 0; fm < 4; ++fm) {
#pragma unroll
    for (int fn = 0; fn < 4; ++fn) {
      int col = n0 + wave_n * 64 + fn * 16 + (lane & 15);
      float bvv = bv[col];
#pragma unroll
      for (int r = 0; r < 4; ++r) {
        int row = m0 + wave_m * 64 + fm * 16 + ((lane >> 4) << 2) + r;
        vout[(size_t)row * 512 + col] = (_Float16)(acc[fm][fn][r] + bvv);
      }
    }
  }
}

// 7) one WAVE per row: top-16; conv gathers HOISTED after the selection loop
//    (16 independent loads pipeline instead of serializing with the shfl
//    chain). Per-row (min,max) -> wmm (no contended atomics).
__global__ __launch_bounds__(256) void topk_conv_kernel(const float* __restrict__ scores,
                                                        const _Float16* __restrict__ vbuf,
                                                        const float* __restrict__ conv_w,
                                                        const float* __restrict__ conv_b,
                                                        float* __restrict__ y,
                                                        float2* __restrict__ wmm) {
  int row = blockIdx.x * 4 + (threadIdx.x >> 6);  // (b*8+h)*65 + g
  int lane = threadIdx.x & 63;
  int g = row % G_;
  int bh = row / G_;
  int b = bh >> 3, h = bh & 7;
  const float* srow = scores + (size_t)(h * G_ + g) * BL_ + b * 1024;

  float s[16];
#pragma unroll
  for (int j = 0; j < 16; ++j) s[j] = srow[j * 64 + lane];  // coalesced

  int sel[16];
#pragma unroll
  for (int r = 0; r < 16; ++r) {
    float bs = s[0];
    int bl = lane;
#pragma unroll
    for (int j = 1; j < 16; ++j) {
      bool t = s[j] > bs;
      bs = t ? s[j] : bs;
      bl = t ? j * 64 + lane : bl;
    }
#pragma unroll
    for (int off = 32; off > 0; off >>= 1) {
      float os = __shfl_xor(bs, off);
      int ol = __shfl_xor(bl, off);
      bool take = (os > bs) || (os == bs && ol < bl);
      bs = take ? os : bs;
      bl = take ? ol : bl;
    }
#pragma unroll
    for (int j = 0; j < 16; ++j)
      if (bl == j * 64 + lane) s[j] = -INFINITY;
    sel[r] = __builtin_amdgcn_readfirstlane(bl);
  }

  const _Float16* vrow = vbuf + (size_t)b * 1024 * 512 + h * 64 + lane;
  float acc = conv_b[g];
#pragma unroll
  for (int r = 0; r < 16; ++r)
    acc += conv_w[g * 16 + r] * (float)vrow[(size_t)sel[r] * 512];

  y[(size_t)row * 64 + lane] = acc;

  float mn = acc, mx = acc;
#pragma unroll
  for (int off = 32; off > 0; off >>= 1) {
    float o = __shfl_xor(mn, off); mn = fminf(mn, o);
    float p = __shfl_xor(mx, off); mx = fmaxf(mx, p);
  }
  if (lane == 0) wmm[row] = make_float2(mn, mx);
}

// 7b) reduce 16640 per-row (min,max) pairs -> mm (130 uncontended atomics)
__global__ __launch_bounds__(256) void minmax_reduce_kernel(const float2* __restrict__ wmm,
                                                            unsigned int* __restrict__ minmax) {
  int i = blockIdx.x * 256 + threadIdx.x;
  float2 v = wmm[i];
  float mn = v.x, mx = v.y;
#pragma unroll
  for (int off = 32; off > 0; off >>= 1) {
    float o = __shfl_xor(mn, off); mn = fminf(mn, o);
    float p = __shfl_xor(mx, off); mx = fmaxf(mx, p);
  }
  __shared__ float smn[4], smx[4];
  int lane = threadIdx.x & 63, wid = threadIdx.x >> 6;
  if (lane == 0) { smn[wid] = mn; smx[wid] = mx; }
  __syncthreads();
  if (threadIdx.x == 0) {
    mn = fminf(fminf(smn[0], smn[1]), fminf(smn[2], smn[3]));
    mx = fmaxf(fmaxf(smx[0], smx[1]), fmaxf(smx[2], smx[3]));
    atomicMin(&minmax[0], f2s(mn));
    atomicMax(&minmax[1], f2s(mx));
  }
}

// 8) z16[b*65+g][h*64+c] = fp16(exp((y[b,h,g,c]-mn)/(mx-mn)))
__global__ void zprep_kernel(const float* __restrict__ y,
                             const unsigned int* __restrict__ minmax,
                             _Float16* __restrict__ z16) {
  int i = blockIdx.x * 256 + threadIdx.x;
  float mn = s2f(minmax[0]);
  float mx = s2f(minmax[1]);
  float inv = 1.f / (mx - mn);
  int c = i & 63;
  int t = i >> 6;
  int g = t % G_;
  int bh = t / G_;
  int b = bh >> 3, h = bh & 7;
  z16[(size_t)(b * G_ + g) * 512 + h * 64 + c] = (_Float16)expf((y[i] - mn) * inv);
}

// 9) out = z @ Wo + bo ; fp16 1-term MFMA, PACKED B (M=2080 guarded).
__global__ __launch_bounds__(256, 2) void out_gemm_kernel(
    const _Float16* __restrict__ z16, const _Float16* __restrict__ wotp,
    const float* __restrict__ bo, float* __restrict__ out) {
  __shared__ char lds[16384];  // z tile [128][64] fp16, slot-swizzled
  const int tid = threadIdx.x;
  const int lane = tid & 63;
  const int wid = tid >> 6;
  const int wave_m = wid >> 1;
  const int wave_n = wid & 1;
  const int m0 = blockIdx.x * 128;
  const int n0 = blockIdx.y * 128;

  f32x4 acc[4][4];
#pragma unroll
  for (int i = 0; i < 4; ++i)
#pragma unroll
    for (int j = 0; j < 4; ++j) acc[i][j] = (f32x4)(0.f);

  for (int k0 = 0; k0 < 512; k0 += 64) {
#pragma unroll
    for (int it = 0; it < 4; ++it) {
      int row = it * 32 + (tid >> 3);
      int grow = m0 + row;
      if (grow > M_OUT_ - 1) grow = M_OUT_ - 1;  // clamp (stays in-bounds)
      int j = tid & 7;
      size_t src = (size_t)grow * 512 + k0 + ((j ^ (row & 7)) << 3);
      gload16(z16 + src, lds + it * 4096 + wid * 1024);
    }
    __syncthreads();
#pragma unroll
    for (int kh = 0; kh < 2; ++kh) {
      f16x8 Bw[4];
#pragma unroll
      for (int fn = 0; fn < 4; ++fn) {
        size_t bo_off = (((size_t)(n0 >> 4) + wave_n * 4 + fn) * 16 +
                         (k0 >> 5) + kh) * 512 + lane * 8;
        Bw[fn] = *(const f16x8*)(wotp + bo_off);
      }
#pragma unroll
      for (int fm = 0; fm < 4; ++fm) {
        int r = wave_m * 64 + fm * 16 + (lane & 15);
        int jl = kh * 4 + (lane >> 4);
        f16x8 Af = *(const f16x8*)(lds + r * 128 + ((jl ^ (r & 7)) << 4));
#pragma unroll
        for (int fn = 0; fn < 4; ++fn)
          acc[fm][fn] = __builtin_amdgcn_mfma_f32_16x16x32_f16(Af, Bw[fn], acc[fm][fn], 0, 0, 0);
      }
    }
    __syncthreads();
  }
#pragma unroll
  for (int fm = 0; fm < 4; ++fm) {
#pragma unroll
    for (int fn = 0; fn < 4; ++fn) {
      int col = n0 + wave_n * 64 + fn * 16 + (lane & 15);
      float bov = bo[col];
#pragma unroll
      for (int r = 0; r < 4; ++r) {
        int row = m0 + wave_m * 64 + fm * 16 + ((lane >> 4) << 2) + r;
        if (row < M_OUT_)
          out[(size_t)row * 512 + col] = acc[fm][fn][r] + bov;
      }
    }
  }
}

extern "C" void kernel_launch(void* const* d_in, const int* in_sizes, int n_in,
                              void* d_out, int out_size, void* d_ws, size_t ws_size,
                              hipStream_t stream) {
  const float* x      = (const float*)d_in[0];
  const float* Wq     = (const float*)d_in[1];
  const float* bq     = (const float*)d_in[2];
  const float* Wk     = (const float*)d_in[3];
  const float* bk     = (const float*)d_in[4];
  const float* Wv     = (const float*)d_in[5];
  const float* bv     = (const float*)d_in[6];
  const float* Wo     = (const float*)d_in[7];
  const float* bo     = (const float*)d_in[8];
  const float* target = (const float*)d_in[9];
  const float* conv_w = (const float*)d_in[10];
  const float* conv_b = (const float*)d_in[11];
  float* out = (float*)d_out;
  (void)bk;

  char* ws = (char*)d_ws;
  _Float16*      th16  = (_Float16*)(ws);                    // 33,554,432
  _Float16*      tl16  = (_Float16*)(ws + 33554432);         // 33,554,432
  _Float16*      vbf   = (_Float16*)(ws + 67108864);         // 33,554,432
  float*         sc    = (float*)(ws + 100663296);           // 68,157,440
  _Float16*      pph   = (_Float16*)(ws + 168820736);        // 655,360
  _Float16*      ppl   = (_Float16*)(ws + 169476096);        // 655,360
  _Float16*      wvtp  = (_Float16*)(ws + 170131456);        // 524,288
  _Float16*      wotp  = (_Float16*)(ws + 170655744);        // 524,288
  float*         qb    = (float*)(ws + 171180032);           // 133,120
  float*         yb    = (float*)(ws + 171313152);           // 4,259,840
  _Float16*      z16   = (_Float16*)(ws + 175572992);        // 2,129,920
  unsigned int*  mm    = (unsigned int*)(ws + 177702912);    // 8
  float2*        wmm   = (float2*)(ws + 177702928);          // 133,120

  hipMemsetAsync(mm, 0xFF, 4, stream);
  hipMemsetAsync((char*)mm + 4, 0x00, 4, stream);

  transform_split_kernel<<<2048, 256, 0, stream>>>(x, th16, tl16, B_ * L_ * D_ / 4);
  wprep_kernel<<<512, 256, 0, stream>>>(Wv, Wo, wvtp, wotp);
  qproj_kernel<<<dim3(G_, 2), 256, 0, stream>>>(target, Wq, bq, qb);
  p_kernel<<<HGP2_, 256, 0, stream>>>(qb, Wk, pph, ppl);
  scores_gemm_kernel<<<1536, 256, 0, stream>>>(th16, tl16, pph, ppl, sc);
  vgemm_kernel<<<dim3(256, 4), 256, 0, stream>>>(th16, wvtp, bv, vbf);
  topk_conv_kernel<<<NROW_ / 4, 256, 0, stream>>>(sc, vbf, conv_w, conv_b, yb, wmm);
  minmax_reduce_kernel<<<NROW_ / 256, 256, 0, stream>>>(wmm, mm);
  zprep_kernel<<<B_ * H_ * G_ * DH_ / 256, 256, 0, stream>>>(yb, mm, z16);
  out_gemm_kernel<<<dim3(17, 4), 256, 0, stream>>>(z16, wotp, bo, out);
}

// Round 21
// 243.491 us; speedup vs baseline: 1.0286x; 1.0286x over previous
//
#include <hip/hip_runtime.h>
#include <math.h>

#define B_  32
#define L_  1024
#define D_  512
#define H_  8
#define G_  65
#define K_  16
#define DH_ 64
#define HG_  (H_ * G_)   // 520
#define HGP2_ 640        // padded p rows (40 m-tiles of 16)
#define BL_  (B_ * L_)   // 32768
#define NROW_ (B_ * H_ * G_)  // 16640
#define M_OUT_ (B_ * G_)      // 2080

typedef _Float16 f16x8 __attribute__((ext_vector_type(8)));
typedef float f32x4 __attribute__((ext_vector_type(4)));

__device__ __forceinline__ unsigned int f2s(float f) {
  unsigned int u = __float_as_uint(f);
  return (u & 0x80000000u) ? ~u : (u | 0x80000000u);
}
__device__ __forceinline__ float s2f(unsigned int u) {
  return __uint_as_float((u & 0x80000000u) ? (u & 0x7FFFFFFFu) : ~u);
}
// fp16 2-plane split, flush-safe: both planes are normal-or-zero fp16 (lo is
// pre-scaled by 2^12). value ~= hi + lo*2^-12 with rel err ~2^-24.
__device__ __forceinline__ void split16(float v, _Float16* h, _Float16* l) {
  _Float16 h0 = (_Float16)v;
  float hf = (float)h0;
  if (fabsf(v) < 6.103515625e-05f) { h0 = (_Float16)0.f; hf = 0.f; }
  *h = h0;
  *l = (_Float16)((v - hf) * 4096.0f);
}
__device__ __forceinline__ void gload16(const void* g, void* l) {
  __builtin_amdgcn_global_load_lds(
      (const __attribute__((address_space(1))) unsigned int*)g,
      (__attribute__((address_space(3))) unsigned int*)l, 16, 0, 0);
}
// packed-fragment index: fragment (tile mt, k-chunk kc), lane slot, 8 elems.
// element (row, c): mt=row>>4, kc=c>>5, lane=((c&31)>>3)*16 + (row&15), e=c&7.
__device__ __forceinline__ size_t pk_idx(int row, int c) {
  return (((size_t)(row >> 4) * 16 + (c >> 5)) << 9) +
         ((((c & 31) >> 3) << 4) + (row & 15)) * 8 + (c & 7);
}

// 1) t = log(relu(x)+1) -> fp16 hi + fp16 scaled-lo
__global__ void transform_split_kernel(const float* __restrict__ x,
                                       _Float16* __restrict__ th16,
                                       _Float16* __restrict__ tl16, int n4) {
  int i = blockIdx.x * blockDim.x + threadIdx.x;
  int stride = gridDim.x * blockDim.x;
  const float4* x4 = (const float4*)x;
  for (; i < n4; i += stride) {
    float4 a = x4[i];
    float t[4];
    t[0] = logf(fmaxf(a.x, 0.f) + 1.f);
    t[1] = logf(fmaxf(a.y, 0.f) + 1.f);
    t[2] = logf(fmaxf(a.z, 0.f) + 1.f);
    t[3] = logf(fmaxf(a.w, 0.f) + 1.f);
    _Float16 h[4], l[4];
#pragma unroll
    for (int j = 0; j < 4; ++j) split16(t[j], &h[j], &l[j]);
    *(ushort4*)&th16[i * 4] = *(ushort4*)h;
    *(ushort4*)&tl16[i * 4] = *(ushort4*)l;
  }
}

// 2) Wv,Wo -> PACKED-fragment fp16 B-operands (contiguous 1KB per fragment)
__global__ __launch_bounds__(256) void wprep_kernel(const float* __restrict__ Wv,
                                                    const float* __restrict__ Wo,
                                                    _Float16* __restrict__ wvtp,
                                                    _Float16* __restrict__ wotp) {
  int n = blockIdx.x;
  for (int k = threadIdx.x; k < 512; k += 256) {
    size_t o = pk_idx(n, k);
    wvtp[o] = (_Float16)Wv[(size_t)k * 512 + n];
    wotp[o] = (_Float16)Wo[(size_t)k * 512 + n];
  }
}

// 3) q = target @ Wq + bq   [G,512] fp32
__global__ __launch_bounds__(256) void qproj_kernel(const float* __restrict__ target,
                                                    const float* __restrict__ Wq,
                                                    const float* __restrict__ bq,
                                                    float* __restrict__ q) {
  int g = blockIdx.x;
  int d = blockIdx.y * 256 + threadIdx.x;
  __shared__ float ts[512];
  for (int i = threadIdx.x; i < 512; i += 256) ts[i] = target[g * 512 + i];
  __syncthreads();
  float acc = bq[d];
  for (int c = 0; c < 512; ++c) acc += ts[c] * Wq[c * 512 + d];
  q[g * 512 + d] = acc;
}

// 4) p[hg][c] -> PACKED fp16 hi/lo planes. One thread per 2 outputs,
//    16 independent float4 loads (r19-proven). rows 520..639 zeroed.
__global__ __launch_bounds__(256) void p_kernel(const float* __restrict__ q,
                                                const float* __restrict__ Wk,
                                                _Float16* __restrict__ pph,
                                                _Float16* __restrict__ ppl) {
  int hg = blockIdx.x;
  int tid = threadIdx.x;
  if (hg >= HG_) {
    for (int c = tid; c < 512; c += 256) {
      size_t o = pk_idx(hg, c);
      pph[o] = (_Float16)0.f;
      ppl[o] = (_Float16)0.f;
    }
    return;
  }
  int h = hg / G_, g = hg % G_;
  __shared__ float4 qs[16];
  if (tid < 16) qs[tid] = *(const float4*)&q[g * 512 + h * 64 + tid * 4];
  __syncthreads();
#pragma unroll
  for (int cc = 0; cc < 2; ++cc) {
    int c = cc * 256 + tid;
    const float4* wr = (const float4*)&Wk[(size_t)c * 512 + h * 64];
    float acc = 0.f;
#pragma unroll
    for (int jj = 0; jj < 16; ++jj) {
      float4 wv = wr[jj];
      float4 qv = qs[jj];
      acc += wv.x * qv.x + wv.y * qv.y + wv.z * qv.z + wv.w * qv.w;
    }
    _Float16 hh, ll;
    split16(acc, &hh, &ll);
    size_t o = pk_idx(hg, c);
    pph[o] = hh;
    ppl[o] = ll;
  }
}

// 5) scores GEMM: S = p . t, fp16 2-plane / 3-product. r18/r19-exact:
//    BK=32 dbuf one-barrier pipeline, packed A staged in LDS.
//    LDS/buf: t 16KB + A 12KB = 28KB; x2 bufs = 56KB; 2 blocks/CU.
//    (r20's 3-buffer counted-vmcnt raised MfmaUtil 22->30% but cost
//    occupancy 2->1 blocks/CU: net regression 60->78us. Reverted.)
__global__ __launch_bounds__(256, 2) void scores_gemm_kernel(
    const _Float16* __restrict__ th16, const _Float16* __restrict__ tl16,
    const _Float16* __restrict__ pph, const _Float16* __restrict__ ppl,
    float* __restrict__ scores) {
  __shared__ char lds[57344];
  const int w = blockIdx.x;
  const int xcd = w & 7;
  const int j = w >> 3;
  const int n0 = (xcd * 32 + j / 6) * 128;
  const int m0 = (j % 6) * 96;
  const int mt0 = (j % 6) * 6;          // m0/16
  const int tid = threadIdx.x;
  const int lane = tid & 63;
  const int wid = tid >> 6;
  const int l16 = lane & 15;
  const int lg = lane >> 4;

  f32x4 acc0[6][2], acc1[6][2];
#pragma unroll
  for (int i = 0; i < 6; ++i)
#pragma unroll
    for (int jj = 0; jj < 2; ++jj) { acc0[i][jj] = (f32x4)(0.f); acc1[i][jj] = (f32x4)(0.f); }

  const int st_row = wid * 16 + (lane >> 2);
  const int st_s   = lane & 3;

  // stage t ([128][32] x2 planes) + A (12 x 1KB fragments, linear)
#define STAGE_SC(buf, ks)                                                      \
  {                                                                            \
    _Pragma("unroll")                                                          \
    for (int it = 0; it < 2; ++it) {                                           \
      int row = it * 64 + st_row;                                              \
      size_t src = (size_t)(n0 + row) * 512 + (ks) * 32 +                      \
                   ((st_s ^ (row & 3)) << 3);                                  \
      char* dst = lds + (buf) * 28672 + it * 4096 + wid * 1024;                \
      gload16(th16 + src, dst);                                                \
      gload16(tl16 + src, dst + 8192);                                         \
    }                                                                          \
    _Pragma("unroll")                                                          \
    for (int i = 0; i < 3; ++i) {                                              \
      int f = wid * 3 + i;            /* 0..11: 0-5 hi, 6-11 lo */             \
      int fm = f >= 6 ? f - 6 : f;                                             \
      const _Float16* sp = (f >= 6) ? ppl : pph;                               \
      size_t src = (((size_t)(mt0 + fm) * 16 + (ks)) << 9) + lane * 8;         \
      gload16(sp + src, lds + (buf) * 28672 + 16384 + f * 1024);               \
    }                                                                          \
  }

  STAGE_SC(0, 0);
  __syncthreads();

  for (int ks = 0; ks < 16; ++ks) {
    const int cur = ks & 1;
    if (ks < 15) STAGE_SC(cur ^ 1, ks + 1);
    // A fragments from LDS (linear, lane*16 -> conflict-free)
    const char* abase = lds + cur * 28672 + 16384;
    f16x8 Ah[6], Al[6];
#pragma unroll
    for (int fm = 0; fm < 6; ++fm) {
      Ah[fm] = *(const f16x8*)(abase + fm * 1024 + lane * 16);
      Al[fm] = *(const f16x8*)(abase + (6 + fm) * 1024 + lane * 16);
    }
    // B fragments from current t buffer
    f16x8 Bh[2], Bl[2];
#pragma unroll
    for (int fn = 0; fn < 2; ++fn) {
      int r = wid * 32 + fn * 16 + l16;
      int addr = cur * 28672 + r * 64 + ((lg ^ (r & 3)) << 4);
      Bh[fn] = *(const f16x8*)(lds + addr);
      Bl[fn] = *(const f16x8*)(lds + addr + 8192);
    }
#pragma unroll
    for (int fm = 0; fm < 6; ++fm) {
#pragma unroll
      for (int fn = 0; fn < 2; ++fn) {
        acc0[fm][fn] = __builtin_amdgcn_mfma_f32_16x16x32_f16(Ah[fm], Bh[fn], acc0[fm][fn], 0, 0, 0);
        acc1[fm][fn] = __builtin_amdgcn_mfma_f32_16x16x32_f16(Ah[fm], Bl[fn], acc1[fm][fn], 0, 0, 0);
        acc1[fm][fn] = __builtin_amdgcn_mfma_f32_16x16x32_f16(Al[fm], Bh[fn], acc1[fm][fn], 0, 0, 0);
      }
    }
    __syncthreads();
  }
#undef STAGE_SC

#pragma unroll
  for (int fm = 0; fm < 6; ++fm) {
    int hg0 = m0 + fm * 16 + ((lane >> 4) << 2);
#pragma unroll
    for (int fn = 0; fn < 2; ++fn) {
      int col = n0 + wid * 32 + fn * 16 + l16;
#pragma unroll
      for (int r = 0; r < 4; ++r) {
        int row = hg0 + r;
        if (row < HG_)
          scores[(size_t)row * BL_ + col] =
              acc0[fm][fn][r] + acc1[fm][fn][r] * 0.000244140625f;
      }
    }
  }
}

// 6) V GEMM: fp16 1-term, PACKED B-loads (contiguous 1KB fragments).
__global__ __launch_bounds__(256, 2) void vgemm_kernel(
    const _Float16* __restrict__ th16, const _Float16* __restrict__ wvtp,
    const float* __restrict__ bv, _Float16* __restrict__ vout) {
  __shared__ char lds[16384];  // t_hi tile [128][64] fp16, slot-swizzled
  const int tid = threadIdx.x;
  const int lane = tid & 63;
  const int wid = tid >> 6;
  const int wave_m = wid >> 1;
  const int wave_n = wid & 1;
  const int m0 = blockIdx.x * 128;
  const int n0 = blockIdx.y * 128;

  f32x4 acc[4][4];
#pragma unroll
  for (int i = 0; i < 4; ++i)
#pragma unroll
    for (int j = 0; j < 4; ++j) acc[i][j] = (f32x4)(0.f);

  for (int k0 = 0; k0 < 512; k0 += 64) {
#pragma unroll
    for (int it = 0; it < 4; ++it) {
      int row = it * 32 + (tid >> 3);
      int j = tid & 7;
      size_t src = (size_t)(m0 + row) * 512 + k0 + ((j ^ (row & 7)) << 3);
      gload16(th16 + src, lds + it * 4096 + wid * 1024);
    }
    __syncthreads();
#pragma unroll
    for (int kh = 0; kh < 2; ++kh) {
      f16x8 Bv[4];
#pragma unroll
      for (int fn = 0; fn < 4; ++fn) {
        size_t bo = (((size_t)(n0 >> 4) + wave_n * 4 + fn) * 16 +
                     (k0 >> 5) + kh) * 512 + lane * 8;
        Bv[fn] = *(const f16x8*)(wvtp + bo);
      }
#pragma unroll
      for (int fm = 0; fm < 4; ++fm) {
        int r = wave_m * 64 + fm * 16 + (lane & 15);
        int jl = kh * 4 + (lane >> 4);
        f16x8 Af = *(const f16x8*)(lds + r * 128 + ((jl ^ (r & 7)) << 4));
#pragma unroll
        for (int fn = 0; fn < 4; ++fn)
          acc[fm][fn] = __builtin_amdgcn_mfma_f32_16x16x32_f16(Af, Bv[fn], acc[fm][fn], 0, 0, 0);
      }
    }
    __syncthreads();
  }
#pragma unroll
  for (int fm = 0; fm < 4; ++fm) {
#pragma unroll
    for (int fn = 0; fn < 4; ++fn) {
      int col = n0 + wave_n * 64 + fn * 16 + (lane & 15);
      float bvv = bv[col];
#pragma unroll
      for (int r = 0; r < 4; ++r) {
        int row = m0 + wave_m * 64 + fm * 16 + ((lane >> 4) << 2) + r;
        vout[(size_t)row * 512 + col] = (_Float16)(acc[fm][fn][r] + bvv);
      }
    }
  }
}

// 7) one WAVE per row: top-16; conv gathers HOISTED after the selection loop
//    (r20-proven). Per-row (min,max) -> wmm (no contended atomics).
__global__ __launch_bounds__(256) void topk_conv_kernel(const float* __restrict__ scores,
                                                        const _Float16* __restrict__ vbuf,
                                                        const float* __restrict__ conv_w,
                                                        const float* __restrict__ conv_b,
                                                        float* __restrict__ y,
                                                        float2* __restrict__ wmm) {
  int row = blockIdx.x * 4 + (threadIdx.x >> 6);  // (b*8+h)*65 + g
  int lane = threadIdx.x & 63;
  int g = row % G_;
  int bh = row / G_;
  int b = bh >> 3, h = bh & 7;
  const float* srow = scores + (size_t)(h * G_ + g) * BL_ + b * 1024;

  float s[16];
#pragma unroll
  for (int j = 0; j < 16; ++j) s[j] = srow[j * 64 + lane];  // coalesced

  int sel[16];
#pragma unroll
  for (int r = 0; r < 16; ++r) {
    float bs = s[0];
    int bl = lane;
#pragma unroll
    for (int j = 1; j < 16; ++j) {
      bool t = s[j] > bs;
      bs = t ? s[j] : bs;
      bl = t ? j * 64 + lane : bl;
    }
#pragma unroll
    for (int off = 32; off > 0; off >>= 1) {
      float os = __shfl_xor(bs, off);
      int ol = __shfl_xor(bl, off);
      bool take = (os > bs) || (os == bs && ol < bl);
      bs = take ? os : bs;
      bl = take ? ol : bl;
    }
#pragma unroll
    for (int j = 0; j < 16; ++j)
      if (bl == j * 64 + lane) s[j] = -INFINITY;
    sel[r] = __builtin_amdgcn_readfirstlane(bl);
  }

  const _Float16* vrow = vbuf + (size_t)b * 1024 * 512 + h * 64 + lane;
  float acc = conv_b[g];
#pragma unroll
  for (int r = 0; r < 16; ++r)
    acc += conv_w[g * 16 + r] * (float)vrow[(size_t)sel[r] * 512];

  y[(size_t)row * 64 + lane] = acc;

  float mn = acc, mx = acc;
#pragma unroll
  for (int off = 32; off > 0; off >>= 1) {
    float o = __shfl_xor(mn, off); mn = fminf(mn, o);
    float p = __shfl_xor(mx, off); mx = fmaxf(mx, p);
  }
  if (lane == 0) wmm[row] = make_float2(mn, mx);
}

// 7b) reduce 16640 per-row (min,max) pairs -> mm (130 uncontended atomics)
__global__ __launch_bounds__(256) void minmax_reduce_kernel(const float2* __restrict__ wmm,
                                                            unsigned int* __restrict__ minmax) {
  int i = blockIdx.x * 256 + threadIdx.x;
  float2 v = wmm[i];
  float mn = v.x, mx = v.y;
#pragma unroll
  for (int off = 32; off > 0; off >>= 1) {
    float o = __shfl_xor(mn, off); mn = fminf(mn, o);
    float p = __shfl_xor(mx, off); mx = fmaxf(mx, p);
  }
  __shared__ float smn[4], smx[4];
  int lane = threadIdx.x & 63, wid = threadIdx.x >> 6;
  if (lane == 0) { smn[wid] = mn; smx[wid] = mx; }
  __syncthreads();
  if (threadIdx.x == 0) {
    mn = fminf(fminf(smn[0], smn[1]), fminf(smn[2], smn[3]));
    mx = fmaxf(fmaxf(smx[0], smx[1]), fmaxf(smx[2], smx[3]));
    atomicMin(&minmax[0], f2s(mn));
    atomicMax(&minmax[1], f2s(mx));
  }
}

// 8) z16[b*65+g][h*64+c] = fp16(exp((y[b,h,g,c]-mn)/(mx-mn)))
__global__ void zprep_kernel(const float* __restrict__ y,
                             const unsigned int* __restrict__ minmax,
                             _Float16* __restrict__ z16) {
  int i = blockIdx.x * 256 + threadIdx.x;
  float mn = s2f(minmax[0]);
  float mx = s2f(minmax[1]);
  float inv = 1.f / (mx - mn);
  int c = i & 63;
  int t = i >> 6;
  int g = t % G_;
  int bh = t / G_;
  int b = bh >> 3, h = bh & 7;
  z16[(size_t)(b * G_ + g) * 512 + h * 64 + c] = (_Float16)expf((y[i] - mn) * inv);
}

// 9) out = z @ Wo + bo ; fp16 1-term MFMA, PACKED B (M=2080 guarded).
__global__ __launch_bounds__(256, 2) void out_gemm_kernel(
    const _Float16* __restrict__ z16, const _Float16* __restrict__ wotp,
    const float* __restrict__ bo, float* __restrict__ out) {
  __shared__ char lds[16384];  // z tile [128][64] fp16, slot-swizzled
  const int tid = threadIdx.x;
  const int lane = tid & 63;
  const int wid = tid >> 6;
  const int wave_m = wid >> 1;
  const int wave_n = wid & 1;
  const int m0 = blockIdx.x * 128;
  const int n0 = blockIdx.y * 128;

  f32x4 acc[4][4];
#pragma unroll
  for (int i = 0; i < 4; ++i)
#pragma unroll
    for (int j = 0; j < 4; ++j) acc[i][j] = (f32x4)(0.f);

  for (int k0 = 0; k0 < 512; k0 += 64) {
#pragma unroll
    for (int it = 0; it < 4; ++it) {
      int row = it * 32 + (tid >> 3);
      int grow = m0 + row;
      if (grow > M_OUT_ - 1) grow = M_OUT_ - 1;  // clamp (stays in-bounds)
      int j = tid & 7;
      size_t src = (size_t)grow * 512 + k0 + ((j ^ (row & 7)) << 3);
      gload16(z16 + src, lds + it * 4096 + wid * 1024);
    }
    __syncthreads();
#pragma unroll
    for (int kh = 0; kh < 2; ++kh) {
      f16x8 Bw[4];
#pragma unroll
      for (int fn = 0; fn < 4; ++fn) {
        size_t bo_off = (((size_t)(n0 >> 4) + wave_n * 4 + fn) * 16 +
                         (k0 >> 5) + kh) * 512 + lane * 8;
        Bw[fn] = *(const f16x8*)(wotp + bo_off);
      }
#pragma unroll
      for (int fm = 0; fm < 4; ++fm) {
        int r = wave_m * 64 + fm * 16 + (lane & 15);
        int jl = kh * 4 + (lane >> 4);
        f16x8 Af = *(const f16x8*)(lds + r * 128 + ((jl ^ (r & 7)) << 4));
#pragma unroll
        for (int fn = 0; fn < 4; ++fn)
          acc[fm][fn] = __builtin_amdgcn_mfma_f32_16x16x32_f16(Af, Bw[fn], acc[fm][fn], 0, 0, 0);
      }
    }
    __syncthreads();
  }
#pragma unroll
  for (int fm = 0; fm < 4; ++fm) {
#pragma unroll
    for (int fn = 0; fn < 4; ++fn) {
      int col = n0 + wave_n * 64 + fn * 16 + (lane & 15);
      float bov = bo[col];
#pragma unroll
      for (int r = 0; r < 4; ++r) {
        int row = m0 + wave_m * 64 + fm * 16 + ((lane >> 4) << 2) + r;
        if (row < M_OUT_)
          out[(size_t)row * 512 + col] = acc[fm][fn][r] + bov;
      }
    }
  }
}

extern "C" void kernel_launch(void* const* d_in, const int* in_sizes, int n_in,
                              void* d_out, int out_size, void* d_ws, size_t ws_size,
                              hipStream_t stream) {
  const float* x      = (const float*)d_in[0];
  const float* Wq     = (const float*)d_in[1];
  const float* bq     = (const float*)d_in[2];
  const float* Wk     = (const float*)d_in[3];
  const float* bk     = (const float*)d_in[4];
  const float* Wv     = (const float*)d_in[5];
  const float* bv     = (const float*)d_in[6];
  const float* Wo     = (const float*)d_in[7];
  const float* bo     = (const float*)d_in[8];
  const float* target = (const float*)d_in[9];
  const float* conv_w = (const float*)d_in[10];
  const float* conv_b = (const float*)d_in[11];
  float* out = (float*)d_out;
  (void)bk;

  char* ws = (char*)d_ws;
  _Float16*      th16  = (_Float16*)(ws);                    // 33,554,432
  _Float16*      tl16  = (_Float16*)(ws + 33554432);         // 33,554,432
  _Float16*      vbf   = (_Float16*)(ws + 67108864);         // 33,554,432
  float*         sc    = (float*)(ws + 100663296);           // 68,157,440
  _Float16*      pph   = (_Float16*)(ws + 168820736);        // 655,360
  _Float16*      ppl   = (_Float16*)(ws + 169476096);        // 655,360
  _Float16*      wvtp  = (_Float16*)(ws + 170131456);        // 524,288
  _Float16*      wotp  = (_Float16*)(ws + 170655744);        // 524,288
  float*         qb    = (float*)(ws + 171180032);           // 133,120
  float*         yb    = (float*)(ws + 171313152);           // 4,259,840
  _Float16*      z16   = (_Float16*)(ws + 175572992);        // 2,129,920
  unsigned int*  mm    = (unsigned int*)(ws + 177702912);    // 8
  float2*        wmm   = (float2*)(ws + 177702928);          // 133,120

  hipMemsetAsync(mm, 0xFF, 4, stream);
  hipMemsetAsync((char*)mm + 4, 0x00, 4, stream);

  transform_split_kernel<<<2048, 256, 0, stream>>>(x, th16, tl16, B_ * L_ * D_ / 4);
  wprep_kernel<<<512, 256, 0, stream>>>(Wv, Wo, wvtp, wotp);
  qproj_kernel<<<dim3(G_, 2), 256, 0, stream>>>(target, Wq, bq, qb);
  p_kernel<<<HGP2_, 256, 0, stream>>>(qb, Wk, pph, ppl);
  scores_gemm_kernel<<<1536, 256, 0, stream>>>(th16, tl16, pph, ppl, sc);
  vgemm_kernel<<<dim3(256, 4), 256, 0, stream>>>(th16, wvtp, bv, vbf);
  topk_conv_kernel<<<NROW_ / 4, 256, 0, stream>>>(sc, vbf, conv_w, conv_b, yb, wmm);
  minmax_reduce_kernel<<<NROW_ / 256, 256, 0, stream>>>(wmm, mm);
  zprep_kernel<<<B_ * H_ * G_ * DH_ / 256, 256, 0, stream>>>(yb, mm, z16);
  out_gemm_kernel<<<dim3(17, 4), 256, 0, stream>>>(z16, wotp, bo, out);
}

// Round 22
// 241.036 us; speedup vs baseline: 1.0391x; 1.0102x over previous
//
#include <hip/hip_runtime.h>
#include <math.h>

#define B_  32
#define L_  1024
#define D_  512
#define H_  8
#define G_  65
#define K_  16
#define DH_ 64
#define HG_  (H_ * G_)   // 520
#define HGP2_ 640        // padded p rows (40 m-tiles of 16)
#define BL_  (B_ * L_)   // 32768
#define NROW_ (B_ * H_ * G_)  // 16640
#define M_OUT_ (B_ * G_)      // 2080

typedef _Float16 f16x8 __attribute__((ext_vector_type(8)));
typedef float f32x4 __attribute__((ext_vector_type(4)));

__device__ __forceinline__ unsigned int f2s(float f) {
  unsigned int u = __float_as_uint(f);
  return (u & 0x80000000u) ? ~u : (u | 0x80000000u);
}
__device__ __forceinline__ float s2f(unsigned int u) {
  return __uint_as_float((u & 0x80000000u) ? (u & 0x7FFFFFFFu) : ~u);
}
// fp16 2-plane split, flush-safe: both planes are normal-or-zero fp16 (lo is
// pre-scaled by 2^12). value ~= hi + lo*2^-12 with rel err ~2^-24.
__device__ __forceinline__ void split16(float v, _Float16* h, _Float16* l) {
  _Float16 h0 = (_Float16)v;
  float hf = (float)h0;
  if (fabsf(v) < 6.103515625e-05f) { h0 = (_Float16)0.f; hf = 0.f; }
  *h = h0;
  *l = (_Float16)((v - hf) * 4096.0f);
}
__device__ __forceinline__ void gload16(const void* g, void* l) {
  __builtin_amdgcn_global_load_lds(
      (const __attribute__((address_space(1))) unsigned int*)g,
      (__attribute__((address_space(3))) unsigned int*)l, 16, 0, 0);
}
// packed-fragment index: fragment (tile mt, k-chunk kc), lane slot, 8 elems.
// element (row, c): mt=row>>4, kc=c>>5, lane=((c&31)>>3)*16 + (row&15), e=c&7.
__device__ __forceinline__ size_t pk_idx(int row, int c) {
  return (((size_t)(row >> 4) * 16 + (c >> 5)) << 9) +
         ((((c & 31) >> 3) << 4) + (row & 15)) * 8 + (c & 7);
}

// 1) t = log(relu(x)+1) -> fp16 hi + fp16 scaled-lo
__global__ void transform_split_kernel(const float* __restrict__ x,
                                       _Float16* __restrict__ th16,
                                       _Float16* __restrict__ tl16, int n4) {
  int i = blockIdx.x * blockDim.x + threadIdx.x;
  int stride = gridDim.x * blockDim.x;
  const float4* x4 = (const float4*)x;
  for (; i < n4; i += stride) {
    float4 a = x4[i];
    float t[4];
    t[0] = logf(fmaxf(a.x, 0.f) + 1.f);
    t[1] = logf(fmaxf(a.y, 0.f) + 1.f);
    t[2] = logf(fmaxf(a.z, 0.f) + 1.f);
    t[3] = logf(fmaxf(a.w, 0.f) + 1.f);
    _Float16 h[4], l[4];
#pragma unroll
    for (int j = 0; j < 4; ++j) split16(t[j], &h[j], &l[j]);
    *(ushort4*)&th16[i * 4] = *(ushort4*)h;
    *(ushort4*)&tl16[i * 4] = *(ushort4*)l;
  }
}

// 2) Wv,Wo -> PACKED-fragment fp16 B-operands (contiguous 1KB per fragment)
__global__ __launch_bounds__(256) void wprep_kernel(const float* __restrict__ Wv,
                                                    const float* __restrict__ Wo,
                                                    _Float16* __restrict__ wvtp,
                                                    _Float16* __restrict__ wotp) {
  int n = blockIdx.x;
  for (int k = threadIdx.x; k < 512; k += 256) {
    size_t o = pk_idx(n, k);
    wvtp[o] = (_Float16)Wv[(size_t)k * 512 + n];
    wotp[o] = (_Float16)Wo[(size_t)k * 512 + n];
  }
}

// 3) q = target @ Wq + bq   [G,512] fp32
__global__ __launch_bounds__(256) void qproj_kernel(const float* __restrict__ target,
                                                    const float* __restrict__ Wq,
                                                    const float* __restrict__ bq,
                                                    float* __restrict__ q) {
  int g = blockIdx.x;
  int d = blockIdx.y * 256 + threadIdx.x;
  __shared__ float ts[512];
  for (int i = threadIdx.x; i < 512; i += 256) ts[i] = target[g * 512 + i];
  __syncthreads();
  float acc = bq[d];
  for (int c = 0; c < 512; ++c) acc += ts[c] * Wq[c * 512 + d];
  q[g * 512 + d] = acc;
}

// 4) p[hg][c] -> PACKED fp16 hi/lo planes. One thread per 2 outputs,
//    16 independent float4 loads (r19-proven). rows 520..639 zeroed.
__global__ __launch_bounds__(256) void p_kernel(const float* __restrict__ q,
                                                const float* __restrict__ Wk,
                                                _Float16* __restrict__ pph,
                                                _Float16* __restrict__ ppl) {
  int hg = blockIdx.x;
  int tid = threadIdx.x;
  if (hg >= HG_) {
    for (int c = tid; c < 512; c += 256) {
      size_t o = pk_idx(hg, c);
      pph[o] = (_Float16)0.f;
      ppl[o] = (_Float16)0.f;
    }
    return;
  }
  int h = hg / G_, g = hg % G_;
  __shared__ float4 qs[16];
  if (tid < 16) qs[tid] = *(const float4*)&q[g * 512 + h * 64 + tid * 4];
  __syncthreads();
#pragma unroll
  for (int cc = 0; cc < 2; ++cc) {
    int c = cc * 256 + tid;
    const float4* wr = (const float4*)&Wk[(size_t)c * 512 + h * 64];
    float acc = 0.f;
#pragma unroll
    for (int jj = 0; jj < 16; ++jj) {
      float4 wv = wr[jj];
      float4 qv = qs[jj];
      acc += wv.x * qv.x + wv.y * qv.y + wv.z * qv.z + wv.w * qv.w;
    }
    _Float16 hh, ll;
    split16(acc, &hh, &ll);
    size_t o = pk_idx(hg, c);
    pph[o] = hh;
    ppl[o] = ll;
  }
}

// 5) scores GEMM: S = p . t, fp16 2-plane / 3-product. 512-THREAD (8-wave)
//    blocks, m-tile 128, n-tile 128: 2 blocks/CU = 16 waves/CU (was 8) to
//    hide the per-step barrier drains. BK=32 dbuf one-barrier pipeline,
//    packed A staged in LDS. LDS/buf: t 16KB + A 16KB = 32KB; x2 = 64KB.
//    Staging: exactly 4 gload16/thread/step (t dst = linear tid*16).
__global__ __launch_bounds__(512, 4) void scores_gemm_kernel(
    const _Float16* __restrict__ th16, const _Float16* __restrict__ tl16,
    const _Float16* __restrict__ pph, const _Float16* __restrict__ ppl,
    float* __restrict__ scores) {
  __shared__ char lds[65536];
  const int w = blockIdx.x;         // 1280 = 8 XCD x (32 n x 5 m)
  const int xcd = w & 7;
  const int j = w >> 3;             // 0..159
  const int n0 = (xcd * 32 + j / 5) * 128;
  const int mt = j % 5;
  const int m0 = mt * 128;
  const int mt0 = mt * 8;           // first 16-row fragment index
  const int tid = threadIdx.x;
  const int lane = tid & 63;
  const int wv = tid >> 6;          // wave 0..7
  const int wm = wv >> 1;           // 0..3 (m quarter: 2 frags)
  const int wn = wv & 1;            // 0..1 (n half: 64 cols)
  const int l16 = lane & 15;
  const int lg = lane >> 4;

  f32x4 acc0[2][4], acc1[2][4];
#pragma unroll
  for (int i = 0; i < 2; ++i)
#pragma unroll
    for (int jj = 0; jj < 4; ++jj) { acc0[i][jj] = (f32x4)(0.f); acc1[i][jj] = (f32x4)(0.f); }

  const int st_row = tid >> 2;      // 0..127
  const int st_s   = tid & 3;

  // stage t ([128][32] x2 planes, 1 gload each) + A (16 x 1KB frags, 2 each)
#define STAGE_SC(buf, ks)                                                      \
  {                                                                            \
    size_t tsrc = (size_t)(n0 + st_row) * 512 + (ks) * 32 +                    \
                  ((st_s ^ (st_row & 3)) << 3);                                \
    char* tb = lds + (buf) * 32768 + tid * 16;                                 \
    gload16(th16 + tsrc, tb);                                                  \
    gload16(tl16 + tsrc, tb + 8192);                                           \
    _Pragma("unroll")                                                          \
    for (int i = 0; i < 2; ++i) {                                              \
      int f = wv * 2 + i;           /* 0..15: 0-7 hi, 8-15 lo */               \
      int fm = f >= 8 ? f - 8 : f;                                             \
      const _Float16* sp = (f >= 8) ? ppl : pph;                               \
      size_t src = (((size_t)(mt0 + fm) * 16 + (ks)) << 9) + lane * 8;         \
      gload16(sp + src, lds + (buf) * 32768 + 16384 + f * 1024);               \
    }                                                                          \
  }

  STAGE_SC(0, 0);
  __syncthreads();

  for (int ks = 0; ks < 16; ++ks) {
    const int cur = ks & 1;
    if (ks < 15) STAGE_SC(cur ^ 1, ks + 1);
    // A fragments from LDS (linear, lane*16 -> conflict-free)
    const char* abase = lds + cur * 32768 + 16384;
    f16x8 Ah[2], Al[2];
#pragma unroll
    for (int fm = 0; fm < 2; ++fm) {
      int f = wm * 2 + fm;
      Ah[fm] = *(const f16x8*)(abase + f * 1024 + lane * 16);
      Al[fm] = *(const f16x8*)(abase + (8 + f) * 1024 + lane * 16);
    }
    // B fragments per-fn (keeps register pressure under the 128 cap)
#pragma unroll
    for (int fn = 0; fn < 4; ++fn) {
      int r = wn * 64 + fn * 16 + l16;
      int addr = cur * 32768 + r * 64 + ((lg ^ (r & 3)) << 4);
      f16x8 Bh = *(const f16x8*)(lds + addr);
      f16x8 Bl = *(const f16x8*)(lds + addr + 8192);
#pragma unroll
      for (int fm = 0; fm < 2; ++fm) {
        acc0[fm][fn] = __builtin_amdgcn_mfma_f32_16x16x32_f16(Ah[fm], Bh, acc0[fm][fn], 0, 0, 0);
        acc1[fm][fn] = __builtin_amdgcn_mfma_f32_16x16x32_f16(Ah[fm], Bl, acc1[fm][fn], 0, 0, 0);
        acc1[fm][fn] = __builtin_amdgcn_mfma_f32_16x16x32_f16(Al[fm], Bh, acc1[fm][fn], 0, 0, 0);
      }
    }
    __syncthreads();
  }
#undef STAGE_SC

#pragma unroll
  for (int fm = 0; fm < 2; ++fm) {
    int hg0 = m0 + (wm * 2 + fm) * 16 + (lg << 2);
#pragma unroll
    for (int fn = 0; fn < 4; ++fn) {
      int col = n0 + wn * 64 + fn * 16 + l16;
#pragma unroll
      for (int r = 0; r < 4; ++r) {
        int row = hg0 + r;
        if (row < HG_)
          scores[(size_t)row * BL_ + col] =
              acc0[fm][fn][r] + acc1[fm][fn][r] * 0.000244140625f;
      }
    }
  }
}

// 6) V GEMM: fp16 1-term, PACKED B-loads (contiguous 1KB fragments).
__global__ __launch_bounds__(256, 2) void vgemm_kernel(
    const _Float16* __restrict__ th16, const _Float16* __restrict__ wvtp,
    const float* __restrict__ bv, _Float16* __restrict__ vout) {
  __shared__ char lds[16384];  // t_hi tile [128][64] fp16, slot-swizzled
  const int tid = threadIdx.x;
  const int lane = tid & 63;
  const int wid = tid >> 6;
  const int wave_m = wid >> 1;
  const int wave_n = wid & 1;
  const int m0 = blockIdx.x * 128;
  const int n0 = blockIdx.y * 128;

  f32x4 acc[4][4];
#pragma unroll
  for (int i = 0; i < 4; ++i)
#pragma unroll
    for (int j = 0; j < 4; ++j) acc[i][j] = (f32x4)(0.f);

  for (int k0 = 0; k0 < 512; k0 += 64) {
#pragma unroll
    for (int it = 0; it < 4; ++it) {
      int row = it * 32 + (tid >> 3);
      int j = tid & 7;
      size_t src = (size_t)(m0 + row) * 512 + k0 + ((j ^ (row & 7)) << 3);
      gload16(th16 + src, lds + it * 4096 + wid * 1024);
    }
    __syncthreads();
#pragma unroll
    for (int kh = 0; kh < 2; ++kh) {
      f16x8 Bv[4];
#pragma unroll
      for (int fn = 0; fn < 4; ++fn) {
        size_t bo = (((size_t)(n0 >> 4) + wave_n * 4 + fn) * 16 +
                     (k0 >> 5) + kh) * 512 + lane * 8;
        Bv[fn] = *(const f16x8*)(wvtp + bo);
      }
#pragma unroll
      for (int fm = 0; fm < 4; ++fm) {
        int r = wave_m * 64 + fm * 16 + (lane & 15);
        int jl = kh * 4 + (lane >> 4);
        f16x8 Af = *(const f16x8*)(lds + r * 128 + ((jl ^ (r & 7)) << 4));
#pragma unroll
        for (int fn = 0; fn < 4; ++fn)
          acc[fm][fn] = __builtin_amdgcn_mfma_f32_16x16x32_f16(Af, Bv[fn], acc[fm][fn], 0, 0, 0);
      }
    }
    __syncthreads();
  }
#pragma unroll
  for (int fm = 0; fm < 4; ++fm) {
#pragma unroll
    for (int fn = 0; fn < 4; ++fn) {
      int col = n0 + wave_n * 64 + fn * 16 + (lane & 15);
      float bvv = bv[col];
#pragma unroll
      for (int r = 0; r < 4; ++r) {
        int row = m0 + wave_m * 64 + fm * 16 + ((lane >> 4) << 2) + r;
        vout[(size_t)row * 512 + col] = (_Float16)(acc[fm][fn][r] + bvv);
      }
    }
  }
}

// 7) one WAVE per row: top-16; conv gathers HOISTED after the selection loop
//    (r20-proven). Per-row (min,max) -> wmm (no contended atomics).
__global__ __launch_bounds__(256) void topk_conv_kernel(const float* __restrict__ scores,
                                                        const _Float16* __restrict__ vbuf,
                                                        const float* __restrict__ conv_w,
                                                        const float* __restrict__ conv_b,
                                                        float* __restrict__ y,
                                                        float2* __restrict__ wmm) {
  int row = blockIdx.x * 4 + (threadIdx.x >> 6);  // (b*8+h)*65 + g
  int lane = threadIdx.x & 63;
  int g = row % G_;
  int bh = row / G_;
  int b = bh >> 3, h = bh & 7;
  const float* srow = scores + (size_t)(h * G_ + g) * BL_ + b * 1024;

  float s[16];
#pragma unroll
  for (int j = 0; j < 16; ++j) s[j] = srow[j * 64 + lane];  // coalesced

  int sel[16];
#pragma unroll
  for (int r = 0; r < 16; ++r) {
    float bs = s[0];
    int bl = lane;
#pragma unroll
    for (int j = 1; j < 16; ++j) {
      bool t = s[j] > bs;
      bs = t ? s[j] : bs;
      bl = t ? j * 64 + lane : bl;
    }
#pragma unroll
    for (int off = 32; off > 0; off >>= 1) {
      float os = __shfl_xor(bs, off);
      int ol = __shfl_xor(bl, off);
      bool take = (os > bs) || (os == bs && ol < bl);
      bs = take ? os : bs;
      bl = take ? ol : bl;
    }
#pragma unroll
    for (int j = 0; j < 16; ++j)
      if (bl == j * 64 + lane) s[j] = -INFINITY;
    sel[r] = __builtin_amdgcn_readfirstlane(bl);
  }

  const _Float16* vrow = vbuf + (size_t)b * 1024 * 512 + h * 64 + lane;
  float acc = conv_b[g];
#pragma unroll
  for (int r = 0; r < 16; ++r)
    acc += conv_w[g * 16 + r] * (float)vrow[(size_t)sel[r] * 512];

  y[(size_t)row * 64 + lane] = acc;

  float mn = acc, mx = acc;
#pragma unroll
  for (int off = 32; off > 0; off >>= 1) {
    float o = __shfl_xor(mn, off); mn = fminf(mn, o);
    float p = __shfl_xor(mx, off); mx = fmaxf(mx, p);
  }
  if (lane == 0) wmm[row] = make_float2(mn, mx);
}

// 7b) reduce 16640 per-row (min,max) pairs -> mm (130 uncontended atomics)
__global__ __launch_bounds__(256) void minmax_reduce_kernel(const float2* __restrict__ wmm,
                                                            unsigned int* __restrict__ minmax) {
  int i = blockIdx.x * 256 + threadIdx.x;
  float2 v = wmm[i];
  float mn = v.x, mx = v.y;
#pragma unroll
  for (int off = 32; off > 0; off >>= 1) {
    float o = __shfl_xor(mn, off); mn = fminf(mn, o);
    float p = __shfl_xor(mx, off); mx = fmaxf(mx, p);
  }
  __shared__ float smn[4], smx[4];
  int lane = threadIdx.x & 63, wid = threadIdx.x >> 6;
  if (lane == 0) { smn[wid] = mn; smx[wid] = mx; }
  __syncthreads();
  if (threadIdx.x == 0) {
    mn = fminf(fminf(smn[0], smn[1]), fminf(smn[2], smn[3]));
    mx = fmaxf(fmaxf(smx[0], smx[1]), fmaxf(smx[2], smx[3]));
    atomicMin(&minmax[0], f2s(mn));
    atomicMax(&minmax[1], f2s(mx));
  }
}

// 8) z16[b*65+g][h*64+c] = fp16(exp((y[b,h,g,c]-mn)/(mx-mn)))
__global__ void zprep_kernel(const float* __restrict__ y,
                             const unsigned int* __restrict__ minmax,
                             _Float16* __restrict__ z16) {
  int i = blockIdx.x * 256 + threadIdx.x;
  float mn = s2f(minmax[0]);
  float mx = s2f(minmax[1]);
  float inv = 1.f / (mx - mn);
  int c = i & 63;
  int t = i >> 6;
  int g = t % G_;
  int bh = t / G_;
  int b = bh >> 3, h = bh & 7;
  z16[(size_t)(b * G_ + g) * 512 + h * 64 + c] = (_Float16)expf((y[i] - mn) * inv);
}

// 9) out = z @ Wo + bo ; fp16 1-term MFMA, PACKED B (M=2080 guarded).
__global__ __launch_bounds__(256, 2) void out_gemm_kernel(
    const _Float16* __restrict__ z16, const _Float16* __restrict__ wotp,
    const float* __restrict__ bo, float* __restrict__ out) {
  __shared__ char lds[16384];  // z tile [128][64] fp16, slot-swizzled
  const int tid = threadIdx.x;
  const int lane = tid & 63;
  const int wid = tid >> 6;
  const int wave_m = wid >> 1;
  const int wave_n = wid & 1;
  const int m0 = blockIdx.x * 128;
  const int n0 = blockIdx.y * 128;

  f32x4 acc[4][4];
#pragma unroll
  for (int i = 0; i < 4; ++i)
#pragma unroll
    for (int j = 0; j < 4; ++j) acc[i][j] = (f32x4)(0.f);

  for (int k0 = 0; k0 < 512; k0 += 64) {
#pragma unroll
    for (int it = 0; it < 4; ++it) {
      int row = it * 32 + (tid >> 3);
      int grow = m0 + row;
      if (grow > M_OUT_ - 1) grow = M_OUT_ - 1;  // clamp (stays in-bounds)
      int j = tid & 7;
      size_t src = (size_t)grow * 512 + k0 + ((j ^ (row & 7)) << 3);
      gload16(z16 + src, lds + it * 4096 + wid * 1024);
    }
    __syncthreads();
#pragma unroll
    for (int kh = 0; kh < 2; ++kh) {
      f16x8 Bw[4];
#pragma unroll
      for (int fn = 0; fn < 4; ++fn) {
        size_t bo_off = (((size_t)(n0 >> 4) + wave_n * 4 + fn) * 16 +
                         (k0 >> 5) + kh) * 512 + lane * 8;
        Bw[fn] = *(const f16x8*)(wotp + bo_off);
      }
#pragma unroll
      for (int fm = 0; fm < 4; ++fm) {
        int r = wave_m * 64 + fm * 16 + (lane & 15);
        int jl = kh * 4 + (lane >> 4);
        f16x8 Af = *(const f16x8*)(lds + r * 128 + ((jl ^ (r & 7)) << 4));
#pragma unroll
        for (int fn = 0; fn < 4; ++fn)
          acc[fm][fn] = __builtin_amdgcn_mfma_f32_16x16x32_f16(Af, Bw[fn], acc[fm][fn], 0, 0, 0);
      }
    }
    __syncthreads();
  }
#pragma unroll
  for (int fm = 0; fm < 4; ++fm) {
#pragma unroll
    for (int fn = 0; fn < 4; ++fn) {
      int col = n0 + wave_n * 64 + fn * 16 + (lane & 15);
      float bov = bo[col];
#pragma unroll
      for (int r = 0; r < 4; ++r) {
        int row = m0 + wave_m * 64 + fm * 16 + ((lane >> 4) << 2) + r;
        if (row < M_OUT_)
          out[(size_t)row * 512 + col] = acc[fm][fn][r] + bov;
      }
    }
  }
}

extern "C" void kernel_launch(void* const* d_in, const int* in_sizes, int n_in,
                              void* d_out, int out_size, void* d_ws, size_t ws_size,
                              hipStream_t stream) {
  const float* x      = (const float*)d_in[0];
  const float* Wq     = (const float*)d_in[1];
  const float* bq     = (const float*)d_in[2];
  const float* Wk     = (const float*)d_in[3];
  const float* bk     = (const float*)d_in[4];
  const float* Wv     = (const float*)d_in[5];
  const float* bv     = (const float*)d_in[6];
  const float* Wo     = (const float*)d_in[7];
  const float* bo     = (const float*)d_in[8];
  const float* target = (const float*)d_in[9];
  const float* conv_w = (const float*)d_in[10];
  const float* conv_b = (const float*)d_in[11];
  float* out = (float*)d_out;
  (void)bk;

  char* ws = (char*)d_ws;
  _Float16*      th16  = (_Float16*)(ws);                    // 33,554,432
  _Float16*      tl16  = (_Float16*)(ws + 33554432);         // 33,554,432
  _Float16*      vbf   = (_Float16*)(ws + 67108864);         // 33,554,432
  float*         sc    = (float*)(ws + 100663296);           // 68,157,440
  _Float16*      pph   = (_Float16*)(ws + 168820736);        // 655,360
  _Float16*      ppl   = (_Float16*)(ws + 169476096);        // 655,360
  _Float16*      wvtp  = (_Float16*)(ws + 170131456);        // 524,288
  _Float16*      wotp  = (_Float16*)(ws + 170655744);        // 524,288
  float*         qb    = (float*)(ws + 171180032);           // 133,120
  float*         yb    = (float*)(ws + 171313152);           // 4,259,840
  _Float16*      z16   = (_Float16*)(ws + 175572992);        // 2,129,920
  unsigned int*  mm    = (unsigned int*)(ws + 177702912);    // 8
  float2*        wmm   = (float2*)(ws + 177702928);          // 133,120

  hipMemsetAsync(mm, 0xFF, 4, stream);
  hipMemsetAsync((char*)mm + 4, 0x00, 4, stream);

  transform_split_kernel<<<2048, 256, 0, stream>>>(x, th16, tl16, B_ * L_ * D_ / 4);
  wprep_kernel<<<512, 256, 0, stream>>>(Wv, Wo, wvtp, wotp);
  qproj_kernel<<<dim3(G_, 2), 256, 0, stream>>>(target, Wq, bq, qb);
  p_kernel<<<HGP2_, 256, 0, stream>>>(qb, Wk, pph, ppl);
  scores_gemm_kernel<<<1280, 512, 0, stream>>>(th16, tl16, pph, ppl, sc);
  vgemm_kernel<<<dim3(256, 4), 256, 0, stream>>>(th16, wvtp, bv, vbf);
  topk_conv_kernel<<<NROW_ / 4, 256, 0, stream>>>(sc, vbf, conv_w, conv_b, yb, wmm);
  minmax_reduce_kernel<<<NROW_ / 256, 256, 0, stream>>>(wmm, mm);
  zprep_kernel<<<B_ * H_ * G_ * DH_ / 256, 256, 0, stream>>>(yb, mm, z16);
  out_gemm_kernel<<<dim3(17, 4), 256, 0, stream>>>(z16, wotp, bo, out);
}

// Round 23
// 235.498 us; speedup vs baseline: 1.0635x; 1.0235x over previous
//
#include <hip/hip_runtime.h>
#include <math.h>

#define B_  32
#define L_  1024
#define D_  512
#define H_  8
#define G_  65
#define K_  16
#define DH_ 64
#define HG_  (H_ * G_)   // 520
#define HGP2_ 640        // padded p rows (40 m-tiles of 16)
#define BL_  (B_ * L_)   // 32768
#define NROW_ (B_ * H_ * G_)  // 16640
#define M_OUT_ (B_ * G_)      // 2080

typedef _Float16 f16x8 __attribute__((ext_vector_type(8)));
typedef float f32x4 __attribute__((ext_vector_type(4)));

__device__ __forceinline__ unsigned int f2s(float f) {
  unsigned int u = __float_as_uint(f);
  return (u & 0x80000000u) ? ~u : (u | 0x80000000u);
}
__device__ __forceinline__ float s2f(unsigned int u) {
  return __uint_as_float((u & 0x80000000u) ? (u & 0x7FFFFFFFu) : ~u);
}
// fp16 2-plane split, flush-safe: both planes are normal-or-zero fp16 (lo is
// pre-scaled by 2^12). value ~= hi + lo*2^-12 with rel err ~2^-24.
__device__ __forceinline__ void split16(float v, _Float16* h, _Float16* l) {
  _Float16 h0 = (_Float16)v;
  float hf = (float)h0;
  if (fabsf(v) < 6.103515625e-05f) { h0 = (_Float16)0.f; hf = 0.f; }
  *h = h0;
  *l = (_Float16)((v - hf) * 4096.0f);
}
__device__ __forceinline__ void gload16(const void* g, void* l) {
  __builtin_amdgcn_global_load_lds(
      (const __attribute__((address_space(1))) unsigned int*)g,
      (__attribute__((address_space(3))) unsigned int*)l, 16, 0, 0);
}
// packed-fragment index: fragment (tile mt, k-chunk kc), lane slot, 8 elems.
__device__ __forceinline__ size_t pk_idx(int row, int c) {
  return (((size_t)(row >> 4) * 16 + (c >> 5)) << 9) +
         ((((c & 31) >> 3) << 4) + (row & 15)) * 8 + (c & 7);
}

// 1) t = log(relu(x)+1) -> fp16 hi + fp16 scaled-lo
__global__ void transform_split_kernel(const float* __restrict__ x,
                                       _Float16* __restrict__ th16,
                                       _Float16* __restrict__ tl16, int n4) {
  int i = blockIdx.x * blockDim.x + threadIdx.x;
  int stride = gridDim.x * blockDim.x;
  const float4* x4 = (const float4*)x;
  for (; i < n4; i += stride) {
    float4 a = x4[i];
    float t[4];
    t[0] = logf(fmaxf(a.x, 0.f) + 1.f);
    t[1] = logf(fmaxf(a.y, 0.f) + 1.f);
    t[2] = logf(fmaxf(a.z, 0.f) + 1.f);
    t[3] = logf(fmaxf(a.w, 0.f) + 1.f);
    _Float16 h[4], l[4];
#pragma unroll
    for (int j = 0; j < 4; ++j) split16(t[j], &h[j], &l[j]);
    *(ushort4*)&th16[i * 4] = *(ushort4*)h;
    *(ushort4*)&tl16[i * 4] = *(ushort4*)l;
  }
}

// 2) Wv,Wo -> PACKED-fragment fp16 B-operands (contiguous 1KB per fragment)
__global__ __launch_bounds__(256) void wprep_kernel(const float* __restrict__ Wv,
                                                    const float* __restrict__ Wo,
                                                    _Float16* __restrict__ wvtp,
                                                    _Float16* __restrict__ wotp) {
  int n = blockIdx.x;
  for (int k = threadIdx.x; k < 512; k += 256) {
    size_t o = pk_idx(n, k);
    wvtp[o] = (_Float16)Wv[(size_t)k * 512 + n];
    wotp[o] = (_Float16)Wo[(size_t)k * 512 + n];
  }
}

// 3) q = target @ Wq + bq   [G,512] fp32
__global__ __launch_bounds__(256) void qproj_kernel(const float* __restrict__ target,
                                                    const float* __restrict__ Wq,
                                                    const float* __restrict__ bq,
                                                    float* __restrict__ q) {
  int g = blockIdx.x;
  int d = blockIdx.y * 256 + threadIdx.x;
  __shared__ float ts[512];
  for (int i = threadIdx.x; i < 512; i += 256) ts[i] = target[g * 512 + i];
  __syncthreads();
  float acc = bq[d];
  for (int c = 0; c < 512; ++c) acc += ts[c] * Wq[c * 512 + d];
  q[g * 512 + d] = acc;
}

// 4) p[hg][c] -> PACKED fp16 hi/lo planes (r19-proven). rows 520..639 zeroed.
__global__ __launch_bounds__(256) void p_kernel(const float* __restrict__ q,
                                                const float* __restrict__ Wk,
                                                _Float16* __restrict__ pph,
                                                _Float16* __restrict__ ppl) {
  int hg = blockIdx.x;
  int tid = threadIdx.x;
  if (hg >= HG_) {
    for (int c = tid; c < 512; c += 256) {
      size_t o = pk_idx(hg, c);
      pph[o] = (_Float16)0.f;
      ppl[o] = (_Float16)0.f;
    }
    return;
  }
  int h = hg / G_, g = hg % G_;
  __shared__ float4 qs[16];
  if (tid < 16) qs[tid] = *(const float4*)&q[g * 512 + h * 64 + tid * 4];
  __syncthreads();
#pragma unroll
  for (int cc = 0; cc < 2; ++cc) {
    int c = cc * 256 + tid;
    const float4* wr = (const float4*)&Wk[(size_t)c * 512 + h * 64];
    float acc = 0.f;
#pragma unroll
    for (int jj = 0; jj < 16; ++jj) {
      float4 wv = wr[jj];
      float4 qv = qs[jj];
      acc += wv.x * qv.x + wv.y * qv.y + wv.z * qv.z + wv.w * qv.w;
    }
    _Float16 hh, ll;
    split16(acc, &hh, &ll);
    size_t o = pk_idx(hg, c);
    pph[o] = hh;
    ppl[o] = ll;
  }
}

// 5+6 MERGED: blocks 0..1279 = scores GEMM (r22-exact 512-thread path);
//    blocks 1280..1791 = V GEMM re-tiled for 512 threads (128 rows x 256
//    cols, 8 waves x 64x64). vgemm blocks dispatch behind scores blocks and
//    backfill CUs as scores drains — removes the kernel-boundary
//    serialization between two independent GEMMs.
__global__ __launch_bounds__(512, 4) void fused_gemms_kernel(
    const _Float16* __restrict__ th16, const _Float16* __restrict__ tl16,
    const _Float16* __restrict__ pph, const _Float16* __restrict__ ppl,
    const _Float16* __restrict__ wvtp, const float* __restrict__ bv,
    float* __restrict__ scores, _Float16* __restrict__ vout) {
  __shared__ char lds[65536];
  const int tid = threadIdx.x;
  const int lane = tid & 63;
  const int wv = tid >> 6;          // wave 0..7
  const int l16 = lane & 15;
  const int lg = lane >> 4;

  if (blockIdx.x < 1280) {
    // ---------------- scores path (r22-exact) ----------------
    const int w = blockIdx.x;       // 1280 = 8 XCD x (32 n x 5 m)
    const int xcd = w & 7;
    const int j = w >> 3;
    const int n0 = (xcd * 32 + j / 5) * 128;
    const int mt = j % 5;
    const int m0 = mt * 128;
    const int mt0 = mt * 8;
    const int wm = wv >> 1;
    const int wn = wv & 1;

    f32x4 acc0[2][4], acc1[2][4];
#pragma unroll
    for (int i = 0; i < 2; ++i)
#pragma unroll
      for (int jj = 0; jj < 4; ++jj) { acc0[i][jj] = (f32x4)(0.f); acc1[i][jj] = (f32x4)(0.f); }

    const int st_row = tid >> 2;
    const int st_s   = tid & 3;

#define STAGE_SC(buf, ks)                                                      \
    {                                                                          \
      size_t tsrc = (size_t)(n0 + st_row) * 512 + (ks) * 32 +                  \
                    ((st_s ^ (st_row & 3)) << 3);                              \
      char* tb = lds + (buf) * 32768 + tid * 16;                               \
      gload16(th16 + tsrc, tb);                                                \
      gload16(tl16 + tsrc, tb + 8192);                                         \
      _Pragma("unroll")                                                        \
      for (int i = 0; i < 2; ++i) {                                            \
        int f = wv * 2 + i;                                                    \
        int fm = f >= 8 ? f - 8 : f;                                           \
        const _Float16* sp = (f >= 8) ? ppl : pph;                             \
        size_t src = (((size_t)(mt0 + fm) * 16 + (ks)) << 9) + lane * 8;       \
        gload16(sp + src, lds + (buf) * 32768 + 16384 + f * 1024);             \
      }                                                                        \
    }

    STAGE_SC(0, 0);
    __syncthreads();

    for (int ks = 0; ks < 16; ++ks) {
      const int cur = ks & 1;
      if (ks < 15) STAGE_SC(cur ^ 1, ks + 1);
      const char* abase = lds + cur * 32768 + 16384;
      f16x8 Ah[2], Al[2];
#pragma unroll
      for (int fm = 0; fm < 2; ++fm) {
        int f = wm * 2 + fm;
        Ah[fm] = *(const f16x8*)(abase + f * 1024 + lane * 16);
        Al[fm] = *(const f16x8*)(abase + (8 + f) * 1024 + lane * 16);
      }
#pragma unroll
      for (int fn = 0; fn < 4; ++fn) {
        int r = wn * 64 + fn * 16 + l16;
        int addr = cur * 32768 + r * 64 + ((lg ^ (r & 3)) << 4);
        f16x8 Bh = *(const f16x8*)(lds + addr);
        f16x8 Bl = *(const f16x8*)(lds + addr + 8192);
#pragma unroll
        for (int fm = 0; fm < 2; ++fm) {
          acc0[fm][fn] = __builtin_amdgcn_mfma_f32_16x16x32_f16(Ah[fm], Bh, acc0[fm][fn], 0, 0, 0);
          acc1[fm][fn] = __builtin_amdgcn_mfma_f32_16x16x32_f16(Ah[fm], Bl, acc1[fm][fn], 0, 0, 0);
          acc1[fm][fn] = __builtin_amdgcn_mfma_f32_16x16x32_f16(Al[fm], Bh, acc1[fm][fn], 0, 0, 0);
        }
      }
      __syncthreads();
    }
#undef STAGE_SC

#pragma unroll
    for (int fm = 0; fm < 2; ++fm) {
      int hg0 = m0 + (wm * 2 + fm) * 16 + (lg << 2);
#pragma unroll
      for (int fn = 0; fn < 4; ++fn) {
        int col = n0 + wn * 64 + fn * 16 + l16;
#pragma unroll
        for (int r = 0; r < 4; ++r) {
          int row = hg0 + r;
          if (row < HG_)
            scores[(size_t)row * BL_ + col] =
                acc0[fm][fn][r] + acc1[fm][fn][r] * 0.000244140625f;
        }
      }
    }
  } else {
    // ---------------- vgemm path: 128 rows x 256 cols, 8 waves ----------
    const int vb = blockIdx.x - 1280;   // 0..511
    const int m0 = (vb & 255) * 128;
    const int nh = vb >> 8;             // 0..1 (n-half of 256)
    const int wm = wv & 1;              // 2 m-halves of 64
    const int wn = wv >> 1;             // 4 n-quarters of 64

    f32x4 acc[4][4];
#pragma unroll
    for (int i = 0; i < 4; ++i)
#pragma unroll
      for (int jj = 0; jj < 4; ++jj) acc[i][jj] = (f32x4)(0.f);

    for (int k0 = 0; k0 < 512; k0 += 64) {
      // stage t_hi [128][64] (16KB): 2 gload16/thread, proven slot swizzle
#pragma unroll
      for (int it = 0; it < 2; ++it) {
        int row = it * 64 + (tid >> 3);
        int j8 = tid & 7;
        size_t src = (size_t)(m0 + row) * 512 + k0 + ((j8 ^ (row & 7)) << 3);
        gload16(th16 + src, lds + it * 8192 + tid * 16);
      }
      __syncthreads();
#pragma unroll
      for (int kh = 0; kh < 2; ++kh) {
        f16x8 Bv[4];
#pragma unroll
        for (int fn = 0; fn < 4; ++fn) {
          size_t bo = (((size_t)(nh * 16 + wn * 4 + fn)) * 16 +
                       (k0 >> 5) + kh) * 512 + lane * 8;
          Bv[fn] = *(const f16x8*)(wvtp + bo);
        }
#pragma unroll
        for (int fm = 0; fm < 4; ++fm) {
          int r = wm * 64 + fm * 16 + l16;
          int jl = kh * 4 + lg;
          f16x8 Af = *(const f16x8*)(lds + r * 128 + ((jl ^ (r & 7)) << 4));
#pragma unroll
          for (int fn = 0; fn < 4; ++fn)
            acc[fm][fn] = __builtin_amdgcn_mfma_f32_16x16x32_f16(Af, Bv[fn], acc[fm][fn], 0, 0, 0);
        }
      }
      __syncthreads();
    }
#pragma unroll
    for (int fm = 0; fm < 4; ++fm) {
#pragma unroll
      for (int fn = 0; fn < 4; ++fn) {
        int col = nh * 256 + wn * 64 + fn * 16 + l16;
        float bvv = bv[col];
#pragma unroll
        for (int r = 0; r < 4; ++r) {
          int row = m0 + wm * 64 + fm * 16 + (lg << 2) + r;
          vout[(size_t)row * 512 + col] = (_Float16)(acc[fm][fn][r] + bvv);
        }
      }
    }
  }
}

// 7) one WAVE per row: top-16; conv gathers HOISTED (r20-proven).
__global__ __launch_bounds__(256) void topk_conv_kernel(const float* __restrict__ scores,
                                                        const _Float16* __restrict__ vbuf,
                                                        const float* __restrict__ conv_w,
                                                        const float* __restrict__ conv_b,
                                                        float* __restrict__ y,
                                                        float2* __restrict__ wmm) {
  int row = blockIdx.x * 4 + (threadIdx.x >> 6);  // (b*8+h)*65 + g
  int lane = threadIdx.x & 63;
  int g = row % G_;
  int bh = row / G_;
  int b = bh >> 3, h = bh & 7;
  const float* srow = scores + (size_t)(h * G_ + g) * BL_ + b * 1024;

  float s[16];
#pragma unroll
  for (int j = 0; j < 16; ++j) s[j] = srow[j * 64 + lane];  // coalesced

  int sel[16];
#pragma unroll
  for (int r = 0; r < 16; ++r) {
    float bs = s[0];
    int bl = lane;
#pragma unroll
    for (int j = 1; j < 16; ++j) {
      bool t = s[j] > bs;
      bs = t ? s[j] : bs;
      bl = t ? j * 64 + lane : bl;
    }
#pragma unroll
    for (int off = 32; off > 0; off >>= 1) {
      float os = __shfl_xor(bs, off);
      int ol = __shfl_xor(bl, off);
      bool take = (os > bs) || (os == bs && ol < bl);
      bs = take ? os : bs;
      bl = take ? ol : bl;
    }
#pragma unroll
    for (int j = 0; j < 16; ++j)
      if (bl == j * 64 + lane) s[j] = -INFINITY;
    sel[r] = __builtin_amdgcn_readfirstlane(bl);
  }

  const _Float16* vrow = vbuf + (size_t)b * 1024 * 512 + h * 64 + lane;
  float acc = conv_b[g];
#pragma unroll
  for (int r = 0; r < 16; ++r)
    acc += conv_w[g * 16 + r] * (float)vrow[(size_t)sel[r] * 512];

  y[(size_t)row * 64 + lane] = acc;

  float mn = acc, mx = acc;
#pragma unroll
  for (int off = 32; off > 0; off >>= 1) {
    float o = __shfl_xor(mn, off); mn = fminf(mn, o);
    float p = __shfl_xor(mx, off); mx = fmaxf(mx, p);
  }
  if (lane == 0) wmm[row] = make_float2(mn, mx);
}

// 7b) reduce 16640 per-row (min,max) pairs -> mm (130 uncontended atomics)
__global__ __launch_bounds__(256) void minmax_reduce_kernel(const float2* __restrict__ wmm,
                                                            unsigned int* __restrict__ minmax) {
  int i = blockIdx.x * 256 + threadIdx.x;
  float2 v = wmm[i];
  float mn = v.x, mx = v.y;
#pragma unroll
  for (int off = 32; off > 0; off >>= 1) {
    float o = __shfl_xor(mn, off); mn = fminf(mn, o);
    float p = __shfl_xor(mx, off); mx = fmaxf(mx, p);
  }
  __shared__ float smn[4], smx[4];
  int lane = threadIdx.x & 63, wid = threadIdx.x >> 6;
  if (lane == 0) { smn[wid] = mn; smx[wid] = mx; }
  __syncthreads();
  if (threadIdx.x == 0) {
    mn = fminf(fminf(smn[0], smn[1]), fminf(smn[2], smn[3]));
    mx = fmaxf(fmaxf(smx[0], smx[1]), fmaxf(smx[2], smx[3]));
    atomicMin(&minmax[0], f2s(mn));
    atomicMax(&minmax[1], f2s(mx));
  }
}

// 8) z16[b*65+g][h*64+c] = fp16(exp((y[b,h,g,c]-mn)/(mx-mn)))
__global__ void zprep_kernel(const float* __restrict__ y,
                             const unsigned int* __restrict__ minmax,
                             _Float16* __restrict__ z16) {
  int i = blockIdx.x * 256 + threadIdx.x;
  float mn = s2f(minmax[0]);
  float mx = s2f(minmax[1]);
  float inv = 1.f / (mx - mn);
  int c = i & 63;
  int t = i >> 6;
  int g = t % G_;
  int bh = t / G_;
  int b = bh >> 3, h = bh & 7;
  z16[(size_t)(b * G_ + g) * 512 + h * 64 + c] = (_Float16)expf((y[i] - mn) * inv);
}

// 9) out = z @ Wo + bo ; fp16 1-term MFMA, PACKED B (M=2080 guarded).
__global__ __launch_bounds__(256, 2) void out_gemm_kernel(
    const _Float16* __restrict__ z16, const _Float16* __restrict__ wotp,
    const float* __restrict__ bo, float* __restrict__ out) {
  __shared__ char lds[16384];  // z tile [128][64] fp16, slot-swizzled
  const int tid = threadIdx.x;
  const int lane = tid & 63;
  const int wid = tid >> 6;
  const int wave_m = wid >> 1;
  const int wave_n = wid & 1;
  const int m0 = blockIdx.x * 128;
  const int n0 = blockIdx.y * 128;

  f32x4 acc[4][4];
#pragma unroll
  for (int i = 0; i < 4; ++i)
#pragma unroll
    for (int j = 0; j < 4; ++j) acc[i][j] = (f32x4)(0.f);

  for (int k0 = 0; k0 < 512; k0 += 64) {
#pragma unroll
    for (int it = 0; it < 4; ++it) {
      int row = it * 32 + (tid >> 3);
      int grow = m0 + row;
      if (grow > M_OUT_ - 1) grow = M_OUT_ - 1;  // clamp (stays in-bounds)
      int j = tid & 7;
      size_t src = (size_t)grow * 512 + k0 + ((j ^ (row & 7)) << 3);
      gload16(z16 + src, lds + it * 4096 + wid * 1024);
    }
    __syncthreads();
#pragma unroll
    for (int kh = 0; kh < 2; ++kh) {
      f16x8 Bw[4];
#pragma unroll
      for (int fn = 0; fn < 4; ++fn) {
        size_t bo_off = (((size_t)(n0 >> 4) + wave_n * 4 + fn) * 16 +
                         (k0 >> 5) + kh) * 512 + lane * 8;
        Bw[fn] = *(const f16x8*)(wotp + bo_off);
      }
#pragma unroll
      for (int fm = 0; fm < 4; ++fm) {
        int r = wave_m * 64 + fm * 16 + (lane & 15);
        int jl = kh * 4 + (lane >> 4);
        f16x8 Af = *(const f16x8*)(lds + r * 128 + ((jl ^ (r & 7)) << 4));
#pragma unroll
        for (int fn = 0; fn < 4; ++fn)
          acc[fm][fn] = __builtin_amdgcn_mfma_f32_16x16x32_f16(Af, Bw[fn], acc[fm][fn], 0, 0, 0);
      }
    }
    __syncthreads();
  }
#pragma unroll
  for (int fm = 0; fm < 4; ++fm) {
#pragma unroll
    for (int fn = 0; fn < 4; ++fn) {
      int col = n0 + wave_n * 64 + fn * 16 + (lane & 15);
      float bov = bo[col];
#pragma unroll
      for (int r = 0; r < 4; ++r) {
        int row = m0 + wave_m * 64 + fm * 16 + ((lane >> 4) << 2) + r;
        if (row < M_OUT_)
          out[(size_t)row * 512 + col] = acc[fm][fn][r] + bov;
      }
    }
  }
}

extern "C" void kernel_launch(void* const* d_in, const int* in_sizes, int n_in,
                              void* d_out, int out_size, void* d_ws, size_t ws_size,
                              hipStream_t stream) {
  const float* x      = (const float*)d_in[0];
  const float* Wq     = (const float*)d_in[1];
  const float* bq     = (const float*)d_in[2];
  const float* Wk     = (const float*)d_in[3];
  const float* bk     = (const float*)d_in[4];
  const float* Wv     = (const float*)d_in[5];
  const float* bv     = (const float*)d_in[6];
  const float* Wo     = (const float*)d_in[7];
  const float* bo     = (const float*)d_in[8];
  const float* target = (const float*)d_in[9];
  const float* conv_w = (const float*)d_in[10];
  const float* conv_b = (const float*)d_in[11];
  float* out = (float*)d_out;
  (void)bk;

  char* ws = (char*)d_ws;
  _Float16*      th16  = (_Float16*)(ws);                    // 33,554,432
  _Float16*      tl16  = (_Float16*)(ws + 33554432);         // 33,554,432
  _Float16*      vbf   = (_Float16*)(ws + 67108864);         // 33,554,432
  float*         sc    = (float*)(ws + 100663296);           // 68,157,440
  _Float16*      pph   = (_Float16*)(ws + 168820736);        // 655,360
  _Float16*      ppl   = (_Float16*)(ws + 169476096);        // 655,360
  _Float16*      wvtp  = (_Float16*)(ws + 170131456);        // 524,288
  _Float16*      wotp  = (_Float16*)(ws + 170655744);        // 524,288
  float*         qb    = (float*)(ws + 171180032);           // 133,120
  float*         yb    = (float*)(ws + 171313152);           // 4,259,840
  _Float16*      z16   = (_Float16*)(ws + 175572992);        // 2,129,920
  unsigned int*  mm    = (unsigned int*)(ws + 177702912);    // 8
  float2*        wmm   = (float2*)(ws + 177702928);          // 133,120

  hipMemsetAsync(mm, 0xFF, 4, stream);
  hipMemsetAsync((char*)mm + 4, 0x00, 4, stream);

  transform_split_kernel<<<2048, 256, 0, stream>>>(x, th16, tl16, B_ * L_ * D_ / 4);
  wprep_kernel<<<512, 256, 0, stream>>>(Wv, Wo, wvtp, wotp);
  qproj_kernel<<<dim3(G_, 2), 256, 0, stream>>>(target, Wq, bq, qb);
  p_kernel<<<HGP2_, 256, 0, stream>>>(qb, Wk, pph, ppl);
  fused_gemms_kernel<<<1792, 512, 0, stream>>>(th16, tl16, pph, ppl, wvtp, bv, sc, vbf);
  topk_conv_kernel<<<NROW_ / 4, 256, 0, stream>>>(sc, vbf, conv_w, conv_b, yb, wmm);
  minmax_reduce_kernel<<<NROW_ / 256, 256, 0, stream>>>(wmm, mm);
  zprep_kernel<<<B_ * H_ * G_ * DH_ / 256, 256, 0, stream>>>(yb, mm, z16);
  out_gemm_kernel<<<dim3(17, 4), 256, 0, stream>>>(z16, wotp, bo, out);
}